// Round 8
// baseline (581.791 us; speedup 1.0000x reference)
//
#include <hip/hip_runtime.h>

// ---------- types ----------
typedef short short8 __attribute__((ext_vector_type(8)));
typedef float f32x4 __attribute__((ext_vector_type(4)));
typedef unsigned int u32x4 __attribute__((ext_vector_type(4)));
typedef unsigned short u16x4 __attribute__((ext_vector_type(4)));
typedef unsigned short u16x8 __attribute__((ext_vector_type(8)));

// ---------- bf16 helpers ----------
__device__ __forceinline__ unsigned short f2bf(float f) {
  unsigned int u = __builtin_bit_cast(unsigned int, f);
  u += 0x7fffu + ((u >> 16) & 1u);
  return (unsigned short)(u >> 16);
}
__device__ __forceinline__ float bf2f(unsigned short h) {
  unsigned int u = ((unsigned int)h) << 16;
  return __builtin_bit_cast(float, u);
}

// ---------- async global->LDS (16B per lane; LDS dst = wave base + lane*16) ----------
__device__ __forceinline__ void gl16(const unsigned short* g, unsigned short* l) {
  __builtin_amdgcn_global_load_lds((const __attribute__((address_space(1))) unsigned int*)g,
                                   (__attribute__((address_space(3))) unsigned int*)l, 16, 0, 0);
}

// ---------- problem constants ----------
#define BB 4
#define SS 2048
#define DD 2048
#define HH 16
#define HD 128
#define MM (BB * SS)  // 8192

// ---------- merged cast fp32 -> bf16 (x + 4 weights) ----------
__global__ void cast_all(const float* __restrict__ x, const float* __restrict__ wq,
                         const float* __restrict__ wk, const float* __restrict__ wv,
                         const float* __restrict__ wo, unsigned short* __restrict__ xb,
                         unsigned short* __restrict__ wqb, unsigned short* __restrict__ wkb,
                         unsigned short* __restrict__ wvb, unsigned short* __restrict__ wob) {
  int i = blockIdx.x * blockDim.x + threadIdx.x;
  const int X4 = (MM * DD) / 4;  // 4194304
  const int W4 = (DD * DD) / 4;  // 1048576
  const float* src;
  unsigned short* dst;
  int off;
  if (i < X4) {
    src = x; dst = xb; off = i;
  } else {
    int t = i - X4;
    int w = t >> 20;
    off = t & (W4 - 1);
    src = (w == 0) ? wq : (w == 1) ? wk : (w == 2) ? wv : wo;
    dst = (w == 0) ? wqb : (w == 1) ? wkb : (w == 2) ? wvb : wob;
  }
  f32x4 v = ((const f32x4*)src)[off];
  u16x4 o;
  o[0] = f2bf(v[0]); o[1] = f2bf(v[1]); o[2] = f2bf(v[2]); o[3] = f2bf(v[3]);
  ((u16x4*)dst)[off] = o;
}

// =====================================================================================
// 256x128 GEMM core, BK=32, 256 thr (4 waves 2Mx2N), per-wave 128x64 (acc[8][4]).
// LDS 48KB (2buf x (A 16KB + B 8KB)) -> 2 independent blocks/CU at 8 waves/CU:
// barrier/staging/epilogue stalls of one block overlap the other block's MFMA.
// LDS packs two 64B K-rows per 128B LDS row; swizzle ck = ((l16&1)*4+quad)^((l16>>1)&7)
// (bank-verified: uniform 8 hits/bank-group per b128). Staging via gl16 with
// inverse-swizzled global source (same involution). vmcnt: prologue 2, steady 2, tail 0.
// =====================================================================================
#define BARRIER asm volatile("s_barrier" ::: "memory")

// Stage a 64-row x 32-col panel half (i-th 64-row group) of operand P into LDS.
// Thread layout: srow/scol precomputed from the packed-row swizzle inverse.
#define STGA(P, R0, t, bufo)                                                        \
  do {                                                                              \
    _Pragma("unroll") for (int i_ = 0; i_ < 4; ++i_)                                \
        gl16((P) + (size_t)((R0) + i_ * 64 + srow) * DD + (size_t)((t) * 32 + scol),\
             lds + (bufo) + i_ * 2048 + wvi * 512);                                 \
  } while (0)
#define STGB(P, C0, t, bufo)                                                        \
  do {                                                                              \
    _Pragma("unroll") for (int i_ = 0; i_ < 2; ++i_)                                \
        gl16((P) + (size_t)((C0) + i_ * 64 + srow) * DD + (size_t)((t) * 32 + scol),\
             lds + (bufo) + 8192 + i_ * 2048 + wvi * 512);                          \
  } while (0)

__device__ __forceinline__ void gemm_core(const unsigned short* __restrict__ Ap,
                                          const unsigned short* __restrict__ Bp,
                                          unsigned short* lds, int rt, int ct,
                                          f32x4 (&acc)[8][4]) {
  const int tid = threadIdx.x;
  const int lane = tid & 63, wvi = tid >> 6;   // wvi in [0,4)
  const int wm = wvi >> 1, wn = wvi & 1;
  const int quad = lane >> 4, l16 = lane & 15;
  // staging inverse: thread's stored chunk ch -> global (row, k-chunk)
  const int sg = tid >> 3;                       // 0..31
  const int ch = (tid & 7) ^ (sg & 7);           // stored chunk index
  const int srow = (sg << 1) | (ch >> 2);        // row within 64-row group
  const int scol = (ch & 3) << 3;                // k element offset (shorts)
  // fragment-read swizzled chunk offset (shorts): ((l16&1)*4+quad) ^ ((l16>>1)&7)
  const int ckA = (((((l16 & 1) << 2) | quad) ^ ((l16 >> 1) & 7)) << 3);
  const int arow = wm * 64 + (l16 >> 1);         // LDS row base for A (+ mi*8, +32 ph1)
  const int brow = wn * 32 + (l16 >> 1);         // LDS row base for B (+ ni*8)
  const int rb = rt * 256, cb = ct * 128;

#pragma unroll
  for (int i = 0; i < 8; ++i)
#pragma unroll
    for (int j = 0; j < 4; ++j) acc[i][j] = f32x4{0.f, 0.f, 0.f, 0.f};

  // ---- prologue: B(0), A(0), B(1); wait tile 0 (keep B(1)'s 2 loads outstanding)
  STGB(Bp, cb, 0, 0);
  STGA(Ap, rb, 0, 0);
  STGB(Bp, cb, 1, 12288);
  asm volatile("s_waitcnt vmcnt(2)" ::: "memory");
  BARRIER;

#pragma unroll 2
  for (int t = 0; t < 64; ++t) {
    const unsigned short* ab = lds + (t & 1) * 12288;
    const unsigned short* bb = ab + 8192;
    const int bufn = ((t + 1) & 1) * 12288;   // next buffer (A(t+1) dest)
    const int bufc = (t & 1) * 12288;         // current buffer (B(t+2) dest)
    short8 aq[4], bf[4];

    // ---------- phase 0: mi 0..3 x ni 0..3 ----------
#pragma unroll
    for (int mi = 0; mi < 4; ++mi)
      aq[mi] = __builtin_bit_cast(short8, *(const u32x4*)(ab + (arow + mi * 8) * 64 + ckA));
#pragma unroll
    for (int ni = 0; ni < 4; ++ni)
      bf[ni] = __builtin_bit_cast(short8, *(const u32x4*)(bb + (brow + ni * 8) * 64 + ckA));
    if (t < 63) STGA(Ap, rb, t + 1, bufn);
    BARRIER;
    __builtin_amdgcn_s_setprio(1);
#pragma unroll
    for (int mi = 0; mi < 4; ++mi)
#pragma unroll
      for (int ni = 0; ni < 4; ++ni)
        acc[mi][ni] = __builtin_amdgcn_mfma_f32_16x16x32_bf16(aq[mi], bf[ni], acc[mi][ni], 0, 0, 0);
    __builtin_amdgcn_s_setprio(0);
    BARRIER;

    // ---------- phase 1: mi 4..7 x ni 0..3 ----------
#pragma unroll
    for (int mi = 0; mi < 4; ++mi)
      aq[mi] = __builtin_bit_cast(short8, *(const u32x4*)(ab + (arow + 32 + mi * 8) * 64 + ckA));
    if (t < 62) STGB(Bp, cb, t + 2, bufc);
    BARRIER;
    __builtin_amdgcn_s_setprio(1);
#pragma unroll
    for (int mi = 0; mi < 4; ++mi)
#pragma unroll
      for (int ni = 0; ni < 4; ++ni)
        acc[4 + mi][ni] =
            __builtin_amdgcn_mfma_f32_16x16x32_bf16(aq[mi], bf[ni], acc[4 + mi][ni], 0, 0, 0);
    __builtin_amdgcn_s_setprio(0);
    if (t < 62) {
      asm volatile("s_waitcnt vmcnt(2)" ::: "memory");  // A(t+1),B(t+1) landed; B(t+2) in flight
      BARRIER;
    } else if (t == 62) {
      asm volatile("s_waitcnt vmcnt(0)" ::: "memory");  // tail: drain A(63)
      BARRIER;
    }
  }
}

// ---------- QKV GEMM (merged) + fused RoPE: z=0 Q (roped+scaled), z=1 K (roped,
// chunk-XOR out-swizzle), z=2 V (standard). XCD-chunked bijective grid swizzle. ----------
__global__ __launch_bounds__(256, 2) void gemm_qkv(const unsigned short* __restrict__ A,
                                                   const unsigned short* __restrict__ W0,
                                                   const unsigned short* __restrict__ W1,
                                                   const unsigned short* __restrict__ W2,
                                                   unsigned short* __restrict__ q_out,
                                                   unsigned short* __restrict__ k_out,
                                                   unsigned short* __restrict__ v_out) {
  __shared__ unsigned short lds[24576];
  // T1: chunked XCD swizzle over 1536 blocks (1536 % 8 == 0 -> bijective).
  const int id = (blockIdx.z << 9) | (blockIdx.y << 4) | blockIdx.x;
  const int nid = (id & 7) * 192 + (id >> 3);
  const int z = nid >> 9;
  const int rt = (nid >> 4) & 31, ct = nid & 15;
  const unsigned short* W = (z == 0) ? W0 : (z == 1) ? W1 : W2;
  unsigned short* outb = (z == 0) ? q_out : (z == 1) ? k_out : v_out;
  f32x4 acc[8][4];
  gemm_core(A, W, lds, rt, ct, acc);

  const int tid = threadIdx.x;
  const int lane = tid & 63, wvi = tid >> 6;
  const int wm = wvi >> 1, wn = wvi & 1;
  const int quad = lane >> 4, l16 = lane & 15;

  if (z == 2) {
    // V: standard (B,H,S,hd) scatter writes
#pragma unroll
    for (int mi = 0; mi < 8; ++mi)
#pragma unroll
      for (int ni = 0; ni < 4; ++ni)
#pragma unroll
        for (int r = 0; r < 4; ++r) {
          int row_g = rt * 256 + wm * 128 + mi * 16 + quad * 4 + r;
          int col_g = ct * 128 + wn * 64 + ni * 16 + l16;
          int b = row_g >> 11, s = row_g & (SS - 1);
          int h = col_g >> 7, d = col_g & (HD - 1);
          outb[(((size_t)(b * HH + h)) * SS + (size_t)s) * HD + (size_t)d] = f2bf(acc[mi][ni][r]);
        }
  } else {
    // Q/K with fused RoPE. Pair (d, d^1) lives in lanes (l16, l16^1): one shfl_xor.
    // Q additionally pre-scaled by 1/sqrt(hd) (softmax scale folded in).
    const float psc = (z == 0) ? 0.08838834764831845f : 1.0f;
    const bool odd = (l16 & 1) != 0;
    const float nl = -0.14391156831212936f;  // -ln(10000)/64
    float inv4[4];
#pragma unroll
    for (int ni = 0; ni < 4; ++ni)
      inv4[ni] = __expf((float)((wn * 64 + ni * 16 + l16) >> 1) * nl);
#pragma unroll
    for (int mi = 0; mi < 8; ++mi)
#pragma unroll
      for (int ni = 0; ni < 4; ++ni)
#pragma unroll
        for (int r = 0; r < 4; ++r) {
          int row_g = rt * 256 + wm * 128 + mi * 16 + quad * 4 + r;
          int col_g = ct * 128 + wn * 64 + ni * 16 + l16;
          int b = row_g >> 11, s = row_g & (SS - 1);
          int h = col_g >> 7, d = col_g & (HD - 1);
          float v = acc[mi][ni][r];
          float p = __shfl_xor(v, 1, 64);
          float ang = (float)s * inv4[ni];
          float cs = __cosf(ang), sn = __sinf(ang);
          float o = (odd ? (p * sn + v * cs) : (v * cs - p * sn)) * psc;
          size_t rowbase = (((size_t)(b * HH + h)) * SS + (size_t)s) * HD;
          if (z == 1) {  // K: chunk-XOR swizzle (chunk = d>>3 XOR s&7) for attn staging
            outb[rowbase + (size_t)((((d >> 3) ^ (s & 7)) << 3) | (d & 7))] = f2bf(o);
          } else {
            outb[rowbase + (size_t)d] = f2bf(o);
          }
        }
  }
}

// ---------- output GEMM: fp32 + bias; XCD-chunked grid swizzle ----------
__global__ __launch_bounds__(256, 2) void gemm_out(const unsigned short* __restrict__ A,
                                                   const unsigned short* __restrict__ W,
                                                   float* __restrict__ outf,
                                                   const float* __restrict__ bias) {
  __shared__ unsigned short lds[24576];
  const int id = (blockIdx.y << 4) | blockIdx.x;          // 0..511
  const int nid = (id & 7) * 64 + (id >> 3);              // bijective (512 % 8 == 0)
  const int rt = nid >> 4, ct = nid & 15;
  f32x4 acc[8][4];
  gemm_core(A, W, lds, rt, ct, acc);

  const int tid = threadIdx.x;
  const int lane = tid & 63, wvi = tid >> 6;
  const int wm = wvi >> 1, wn = wvi & 1;
  const int quad = lane >> 4, l16 = lane & 15;
#pragma unroll
  for (int mi = 0; mi < 8; ++mi)
#pragma unroll
    for (int ni = 0; ni < 4; ++ni)
#pragma unroll
      for (int r = 0; r < 4; ++r) {
        int row_g = rt * 256 + wm * 128 + mi * 16 + quad * 4 + r;
        int col_g = ct * 128 + wn * 64 + ni * 16 + l16;
        outf[(size_t)row_g * DD + col_g] = acc[mi][ni][r] + bias[col_g];
      }
}

// ---------- Flash attention v9 (unchanged — verified) ----------
__global__ __launch_bounds__(256, 2) void attn_kernel(const unsigned short* __restrict__ qb,
                                                      const unsigned short* __restrict__ kb,
                                                      const unsigned short* __restrict__ vb,
                                                      unsigned short* __restrict__ ctxb) {
  __shared__ unsigned short lds[32768];  // Kt[2][8192] | Vt[8192] | P[4][2048]
  const int tid = threadIdx.x;
  const int g0 = blockIdx.x;
  const int g = (g0 & 7) * 128 + (g0 >> 3);  // XCD-bijective (1024 % 8 == 0)
  const int bh = g >> 4;             // 0..63
  const int qa = 15 - (g & 15);      // longest-first within bh
  const int lane = tid & 63, wvi = tid >> 6;   // wvi in [0,4)
  const int quad = lane >> 4, l16 = lane & 15;
  const size_t bhq = (size_t)bh * SS * HD;
  const int qrow = qa * 128 + wvi * 32;
  const int b = bh >> 4, h = bh & (HH - 1);
  unsigned short* Pw = lds + 24576 + wvi * 2048;
  unsigned short* Vt = lds + 16384;
  const int kcol = l16 * 8;
  f32x4 zero = {0.f, 0.f, 0.f, 0.f};

  short8 qf[2][4];
#pragma unroll
  for (int rb = 0; rb < 2; ++rb)
#pragma unroll
    for (int ks = 0; ks < 4; ++ks)
      qf[rb][ks] = __builtin_bit_cast(
          short8,
          *(const u32x4*)(qb + bhq + (size_t)(qrow + rb * 16 + l16) * HD + ks * 32 + quad * 8));

  f32x4 acc[2][8];
#pragma unroll
  for (int rb = 0; rb < 2; ++rb)
#pragma unroll
    for (int dt = 0; dt < 8; ++dt) acc[rb][dt] = zero;
  float lpart[2][4] = {{0.f, 0.f, 0.f, 0.f}, {0.f, 0.f, 0.f, 0.f}};

  const int ntile = 2 * qa + 2;

  // ---- prologue: K(0) via gl16 -> Kt[0]; V(0) via regs -> Vt
  {
    u32x4 pva0, pvb0, pva1, pvb1;
    {
      const unsigned short* vs0 = vb + bhq + (size_t)(2 * (tid & 31)) * HD + (tid >> 5) * 8;
      pva0 = *(const u32x4*)vs0;
      pvb0 = *(const u32x4*)(vs0 + HD);
      const int u = tid + 256;
      const unsigned short* vs1 = vb + bhq + (size_t)(2 * (u & 31)) * HD + (u >> 5) * 8;
      pva1 = *(const u32x4*)vs1;
      pvb1 = *(const u32x4*)(vs1 + HD);
    }
#pragma unroll
    for (int r = 0; r < 4; ++r)
      gl16(kb + bhq + (size_t)(r * 16 + wvi * 4 + quad) * HD + kcol,
           lds + (r * 16 + wvi * 4) * 128);
    unsigned int* vw = (unsigned int*)Vt;
    {
      int rr = tid & 31, c = tid >> 5;
      u16x8 va = __builtin_bit_cast(u16x8, pva0);
      u16x8 vb2 = __builtin_bit_cast(u16x8, pvb0);
#pragma unroll
      for (int j = 0; j < 8; ++j)
        vw[(c * 8 + j) * 32 + (((rr >> 2) ^ j) << 2) + (rr & 3)] =
            (unsigned int)va[j] | ((unsigned int)vb2[j] << 16);
      const int u = tid + 256;
      rr = u & 31; c = u >> 5;
      va = __builtin_bit_cast(u16x8, pva1);
      vb2 = __builtin_bit_cast(u16x8, pvb1);
#pragma unroll
      for (int j = 0; j < 8; ++j)
        vw[(c * 8 + j) * 32 + (((rr >> 2) ^ j) << 2) + (rr & 3)] =
            (unsigned int)va[j] | ((unsigned int)vb2[j] << 16);
    }
    __syncthreads();
  }

  for (int kt = 0; kt < ntile; ++kt) {
    const int kv0 = kt * 64;
    const unsigned short* Kc = lds + (kt & 1) * 8192;
    const int nxt = ((kt + 1) & 1) * 8192;
    const bool hasnext = (kt + 1 < ntile);

    // ---- issue prefetch of tile t+1: V -> regs, K -> gl16 into idle K buffer
    u32x4 pva0, pvb0, pva1, pvb1;
    if (hasnext) {
      const int kvn = kv0 + 64;
      const unsigned short* vs0 = vb + bhq + (size_t)(kvn + 2 * (tid & 31)) * HD + (tid >> 5) * 8;
      pva0 = *(const u32x4*)vs0;
      pvb0 = *(const u32x4*)(vs0 + HD);
      const int u = tid + 256;
      const unsigned short* vs1 = vb + bhq + (size_t)(kvn + 2 * (u & 31)) * HD + (u >> 5) * 8;
      pva1 = *(const u32x4*)vs1;
      pvb1 = *(const u32x4*)(vs1 + HD);
#pragma unroll
      for (int r = 0; r < 4; ++r)
        gl16(kb + bhq + (size_t)(kvn + r * 16 + wvi * 4 + quad) * HD + kcol,
             lds + nxt + (r * 16 + wvi * 4) * 128);
    }

    // ---- QK^T: kf read once, feeds both row-blocks
    f32x4 sc0[4], sc1[4];
#pragma unroll
    for (int nt = 0; nt < 4; ++nt) {
      sc0[nt] = zero;
      sc1[nt] = zero;
#pragma unroll
      for (int ks = 0; ks < 4; ++ks) {
        short8 kf = __builtin_bit_cast(
            short8, *(const u32x4*)(Kc + (nt * 16 + l16) * 128 +
                                    (((ks * 4 + quad) ^ (l16 & 7)) << 3)));
        sc0[nt] = __builtin_amdgcn_mfma_f32_16x16x32_bf16(qf[0][ks], kf, sc0[nt], 0, 0, 0);
        sc1[nt] = __builtin_amdgcn_mfma_f32_16x16x32_bf16(qf[1][ks], kf, sc1[nt], 0, 0, 0);
      }
    }

    // ---- softmax (fixed max), P -> per-wave private LDS (v5-verified formulas)
    const bool dm = (kt >= ntile - 2);
    if (dm) {
#pragma unroll
      for (int r = 0; r < 4; ++r) {
        int p15 = quad * 4 + r;
#pragma unroll
        for (int nt = 0; nt < 4; ++nt) {
          int col = kv0 + nt * 16 + l16;
          int el = p15 * 64 + ((((nt * 2 + (l16 >> 3)) + p15 + 4 * (p15 >> 3)) & 7) << 3) +
                   (l16 & 7);
          float pv0 = (col > qrow + p15) ? 0.f : __expf(sc0[nt][r]);
          lpart[0][r] += pv0;
          Pw[el] = f2bf(pv0);
          float pv1 = (col > qrow + 16 + p15) ? 0.f : __expf(sc1[nt][r]);
          lpart[1][r] += pv1;
          Pw[1024 + el] = f2bf(pv1);
        }
      }
    } else {
#pragma unroll
      for (int r = 0; r < 4; ++r) {
        int p15 = quad * 4 + r;
#pragma unroll
        for (int nt = 0; nt < 4; ++nt) {
          int el = p15 * 64 + ((((nt * 2 + (l16 >> 3)) + p15 + 4 * (p15 >> 3)) & 7) << 3) +
                   (l16 & 7);
          float pv0 = __expf(sc0[nt][r]);
          lpart[0][r] += pv0;
          Pw[el] = f2bf(pv0);
          float pv1 = __expf(sc1[nt][r]);
          lpart[1][r] += pv1;
          Pw[1024 + el] = f2bf(pv1);
        }
      }
    }

    // ---- PV: vf read once, feeds both row-blocks
#pragma unroll
    for (int ks2 = 0; ks2 < 2; ++ks2) {
      const int pk = (((ks2 * 4 + quad) + l16 + 4 * (l16 >> 3)) & 7) << 3;
      short8 pf0 = __builtin_bit_cast(short8, *(const u32x4*)(Pw + l16 * 64 + pk));
      short8 pf1 = __builtin_bit_cast(short8, *(const u32x4*)(Pw + 1024 + l16 * 64 + pk));
#pragma unroll
      for (int dt = 0; dt < 8; ++dt) {
        short8 vf = __builtin_bit_cast(
            short8, *(const u32x4*)(Vt + (dt * 16 + l16) * 64 +
                                    (((ks2 * 4 + quad) ^ (l16 & 7)) << 3)));
        acc[0][dt] = __builtin_amdgcn_mfma_f32_16x16x32_bf16(pf0, vf, acc[0][dt], 0, 0, 0);
        acc[1][dt] = __builtin_amdgcn_mfma_f32_16x16x32_bf16(pf1, vf, acc[1][dt], 0, 0, 0);
      }
    }

    __syncthreads();  // all waves done reading Vt (and K gl16 for t+1 drained)

    // ---- write prefetched V(t+1) into Vt, publish with second barrier
    if (hasnext) {
      unsigned int* vw = (unsigned int*)Vt;
      int rr = tid & 31, c = tid >> 5;
      u16x8 va = __builtin_bit_cast(u16x8, pva0);
      u16x8 vb2 = __builtin_bit_cast(u16x8, pvb0);
#pragma unroll
      for (int j = 0; j < 8; ++j)
        vw[(c * 8 + j) * 32 + (((rr >> 2) ^ j) << 2) + (rr & 3)] =
            (unsigned int)va[j] | ((unsigned int)vb2[j] << 16);
      const int u = tid + 256;
      rr = u & 31; c = u >> 5;
      va = __builtin_bit_cast(u16x8, pva1);
      vb2 = __builtin_bit_cast(u16x8, pvb1);
#pragma unroll
      for (int j = 0; j < 8; ++j)
        vw[(c * 8 + j) * 32 + (((rr >> 2) ^ j) << 2) + (rr & 3)] =
            (unsigned int)va[j] | ((unsigned int)vb2[j] << 16);
      __syncthreads();
    }
  }

  // epilogue: 16-lane reduction per row, ctx (B,S,D) bf16
#pragma unroll
  for (int rb = 0; rb < 2; ++rb) {
    float rl[4];
#pragma unroll
    for (int r = 0; r < 4; ++r) {
      float rs = lpart[rb][r];
#pragma unroll
      for (int off = 1; off < 16; off <<= 1) rs += __shfl_xor(rs, off, 64);
      rl[r] = 1.0f / rs;
    }
#pragma unroll
    for (int dt = 0; dt < 8; ++dt)
#pragma unroll
      for (int r = 0; r < 4; ++r) {
        int row = qrow + rb * 16 + quad * 4 + r;
        ctxb[((size_t)(b * SS + row)) * DD + h * HD + dt * 16 + l16] =
            f2bf(acc[rb][dt][r] * rl[r]);
      }
  }
}

// ---------- launch ----------
extern "C" void kernel_launch(void* const* d_in, const int* in_sizes, int n_in,
                              void* d_out, int out_size, void* d_ws, size_t ws_size,
                              hipStream_t stream) {
  const float* x = (const float*)d_in[0];
  const float* wq = (const float*)d_in[1];
  const float* wk = (const float*)d_in[2];
  const float* wv = (const float*)d_in[3];
  const float* wo = (const float*)d_in[4];
  const float* bo = (const float*)d_in[5];
  float* out = (float*)d_out;

  unsigned short* xb = (unsigned short*)d_ws;
  unsigned short* wqb = xb + (size_t)MM * DD;
  unsigned short* wkb = wqb + (size_t)DD * DD;
  unsigned short* wvb = wkb + (size_t)DD * DD;
  unsigned short* wob = wvb + (size_t)DD * DD;
  unsigned short* qb = wob + (size_t)DD * DD;
  unsigned short* kb = qb + (size_t)MM * DD;
  unsigned short* vb = kb + (size_t)MM * DD;
  unsigned short* ctxb = vb + (size_t)MM * DD;

  cast_all<<<(2 * MM * DD / 4) / 256, 256, 0, stream>>>(x, wq, wk, wv, wo, xb, wqb, wkb, wvb, wob);

  dim3 gg(DD / 128, MM / 256, 3);
  gemm_qkv<<<gg, 256, 0, stream>>>(xb, wqb, wkb, wvb, qb, kb, vb);

  attn_kernel<<<1024, 256, 0, stream>>>(qb, kb, vb, ctxb);

  dim3 go(DD / 128, MM / 256);
  gemm_out<<<go, 256, 0, stream>>>(ctxb, wob, out, bo);
}